// Round 1
// baseline (284.951 us; speedup 1.0000x reference)
//
#include <hip/hip_runtime.h>

// Problem constants (from reference setup_inputs):
//   input  [TP=8, T=8192, H=4096] fp32
//   residual [T, H] fp32
//   norm_weight [H] fp32
// Outputs (concatenated in d_out): out [T,H] fp32, residual_out [T,H] fp32.
constexpr int TP = 8;
constexpr int NT = 8192;
constexpr int H  = 4096;
constexpr float EPS = 1e-6f;

// One block per token row. 256 threads, each handles (H/4)/256 = 4 float4
// chunks. Memory-bound: everything vectorized 16B/lane, row data kept in
// registers between the sum pass and the normalize pass.
__global__ __launch_bounds__(256) void fused_ar_addres_rmsnorm(
    const float* __restrict__ in,      // [TP, T, H]
    const float* __restrict__ res,     // [T, H]
    const float* __restrict__ w,       // [H]
    float* __restrict__ out,           // [T, H]
    float* __restrict__ res_out)       // [T, H]
{
    const int row = blockIdx.x;
    const int tid = threadIdx.x;
    const size_t row4 = (size_t)row * (H / 4);     // row offset in float4 units
    constexpr size_t RANK_STRIDE4 = (size_t)NT * (H / 4);

    const float4* __restrict__ in4  = reinterpret_cast<const float4*>(in);
    const float4* __restrict__ res4 = reinterpret_cast<const float4*>(res);
    const float4* __restrict__ w4   = reinterpret_cast<const float4*>(w);
    float4* __restrict__ out4 = reinterpret_cast<float4*>(out);
    float4* __restrict__ ro4  = reinterpret_cast<float4*>(res_out);

    constexpr int CH = (H / 4) / 256;  // 4 chunks/thread
    float4 acc[CH];
    float ssq = 0.0f;

    #pragma unroll
    for (int i = 0; i < CH; ++i) {
        const int c = i * 256 + tid;               // float4 column
        float4 s = res4[row4 + c];
        #pragma unroll
        for (int r = 0; r < TP; ++r) {
            float4 v = in4[(size_t)r * RANK_STRIDE4 + row4 + c];
            s.x += v.x; s.y += v.y; s.z += v.z; s.w += v.w;
        }
        acc[i] = s;
        ro4[row4 + c] = s;                          // residual_out
        ssq = fmaf(s.x, s.x, ssq);
        ssq = fmaf(s.y, s.y, ssq);
        ssq = fmaf(s.z, s.z, ssq);
        ssq = fmaf(s.w, s.w, ssq);
    }

    // Block reduction of sum-of-squares: 64-lane wave shuffle, then LDS
    // across the 4 waves.
    #pragma unroll
    for (int off = 32; off > 0; off >>= 1)
        ssq += __shfl_down(ssq, off, 64);

    __shared__ float sdata[4];
    const int lane = tid & 63;
    const int wave = tid >> 6;
    if (lane == 0) sdata[wave] = ssq;
    __syncthreads();
    const float total = sdata[0] + sdata[1] + sdata[2] + sdata[3];
    const float inv = rsqrtf(total * (1.0f / (float)H) + EPS);

    #pragma unroll
    for (int i = 0; i < CH; ++i) {
        const int c = i * 256 + tid;
        const float4 g = w4[c];                     // 16 KiB, L1/L2 resident
        const float4 s = acc[i];
        float4 o;
        o.x = s.x * inv * g.x;
        o.y = s.y * inv * g.y;
        o.z = s.z * inv * g.z;
        o.w = s.w * inv * g.w;
        out4[row4 + c] = o;
    }
}

extern "C" void kernel_launch(void* const* d_in, const int* in_sizes, int n_in,
                              void* d_out, int out_size, void* d_ws, size_t ws_size,
                              hipStream_t stream) {
    const float* in  = (const float*)d_in[0];
    const float* res = (const float*)d_in[1];
    const float* w   = (const float*)d_in[2];
    float* out = (float*)d_out;
    float* res_out = out + (size_t)NT * H;   // outputs concatenated: out, residual_out

    fused_ar_addres_rmsnorm<<<dim3(NT), dim3(256), 0, stream>>>(in, res, w, out, res_out);
}

// Round 2
// 249.458 us; speedup vs baseline: 1.1423x; 1.1423x over previous
//
#include <hip/hip_runtime.h>

// Problem: out = RMSNorm(sum_tp(input) + residual) * w ; also emit residual_out.
//   input  [TP=8, T=8192, H=4096] fp32 ; residual [T,H] ; norm_weight [H]
// Outputs concatenated in d_out: out [T,H], residual_out [T,H].
// Memory-bound: 1.476 GB compulsory traffic, zero reuse except weight.
constexpr int TP = 8;
constexpr int NT = 8192;
constexpr int H  = 4096;
constexpr float EPS = 1e-6f;

// Native vector type so __builtin_nontemporal_load/store accept it
// (HIP's float4 is a wrapper class; clang's builtin needs scalar/vector).
typedef float f32x4 __attribute__((ext_vector_type(4)));

// One block per token row. 256 threads x 4 float4 chunks each.
// All streaming traffic (input, residual, both outputs) is nontemporal to
// avoid L2/LLC allocation thrash; weight stays temporal (reused by all rows).
__global__ __launch_bounds__(256) void fused_ar_addres_rmsnorm(
    const f32x4* __restrict__ in4,     // [TP*T*H/4]
    const f32x4* __restrict__ res4,    // [T*H/4]
    const f32x4* __restrict__ w4,      // [H/4]
    f32x4* __restrict__ out4,          // [T*H/4]
    f32x4* __restrict__ ro4)           // [T*H/4]
{
    const int row = blockIdx.x;
    const int tid = threadIdx.x;
    const size_t row4 = (size_t)row * (H / 4);
    constexpr size_t RANK_STRIDE4 = (size_t)NT * (H / 4);

    constexpr int CH = (H / 4) / 256;  // 4 chunks/thread
    f32x4 acc[CH];
    float ssq = 0.0f;

    #pragma unroll
    for (int i = 0; i < CH; ++i) {
        const int c = i * 256 + tid;               // float4 column
        f32x4 s = __builtin_nontemporal_load(&res4[row4 + c]);
        #pragma unroll
        for (int r = 0; r < TP; ++r) {
            f32x4 v = __builtin_nontemporal_load(&in4[(size_t)r * RANK_STRIDE4 + row4 + c]);
            s += v;
        }
        acc[i] = s;
        __builtin_nontemporal_store(s, &ro4[row4 + c]);   // residual_out
        ssq = fmaf(s.x, s.x, ssq);
        ssq = fmaf(s.y, s.y, ssq);
        ssq = fmaf(s.z, s.z, ssq);
        ssq = fmaf(s.w, s.w, ssq);
    }

    // Block reduction of sum-of-squares: 64-lane wave shuffle + LDS across waves.
    #pragma unroll
    for (int off = 32; off > 0; off >>= 1)
        ssq += __shfl_down(ssq, off, 64);

    __shared__ float sdata[4];
    const int lane = tid & 63;
    const int wave = tid >> 6;
    if (lane == 0) sdata[wave] = ssq;
    __syncthreads();
    const float total = sdata[0] + sdata[1] + sdata[2] + sdata[3];
    const float inv = rsqrtf(total * (1.0f / (float)H) + EPS);

    #pragma unroll
    for (int i = 0; i < CH; ++i) {
        const int c = i * 256 + tid;
        const f32x4 g = w4[c];                     // 16 KiB, cached (reused)
        const f32x4 s = acc[i];
        f32x4 o = s * inv * g;
        __builtin_nontemporal_store(o, &out4[row4 + c]);
    }
}

extern "C" void kernel_launch(void* const* d_in, const int* in_sizes, int n_in,
                              void* d_out, int out_size, void* d_ws, size_t ws_size,
                              hipStream_t stream) {
    const f32x4* in  = (const f32x4*)d_in[0];
    const f32x4* res = (const f32x4*)d_in[1];
    const f32x4* w   = (const f32x4*)d_in[2];
    f32x4* out = (f32x4*)d_out;
    f32x4* res_out = out + (size_t)NT * (H / 4);   // outputs concatenated: out, residual_out

    fused_ar_addres_rmsnorm<<<dim3(NT), dim3(256), 0, stream>>>(in, res, w, out, res_out);
}